// Round 7
// baseline (341.291 us; speedup 1.0000x reference)
//
#include <hip/hip_runtime.h>
#include <math.h>

#define T_ 16
#define B_ 512
#define N_ 8192
#define G_ 39
#define ENC_ 128
#define TH_ 64
#define MROWS 8704          // B_ + N_
#define GATE 512            // 4*ENC_
#define KCAT 192            // TH_ + ENC_
#define SCALE_ 0.08838834764831845f
#define LNEPS 1e-5f
#define NBLK2 272           // MROWS/32

typedef short bf16x8 __attribute__((ext_vector_type(8)));
typedef float f32x4  __attribute__((ext_vector_type(4)));

__device__ __forceinline__ float sigm(float x){ return 1.0f/(1.0f+expf(-x)); }
__device__ __forceinline__ float rcpf(float x){ return __builtin_amdgcn_rcpf(x); }
__device__ __forceinline__ float sigm_f(float x){ return rcpf(1.0f + __expf(-x)); }
__device__ __forceinline__ float tanh_f(float x){ return 1.0f - 2.0f*rcpf(__expf(2.0f*x) + 1.0f); }
__device__ __forceinline__ unsigned short f2bf(float f){
  unsigned int u = __float_as_uint(f);
  unsigned int r = u + 0x7FFFu + ((u>>16)&1u);
  return (unsigned short)(r>>16);
}
__device__ __forceinline__ float bf2f(unsigned short h){
  return __uint_as_float(((unsigned int)h)<<16);
}

// ================= prep: convert weights to bf16, build fused biases =================
__global__ __launch_bounds__(256) void k_prep(
    const float* __restrict__ Wih, const float* __restrict__ Whh,
    const float* __restrict__ bih, const float* __restrict__ bhh,
    const float* __restrict__ Wk,  const float* __restrict__ bk,
    const float* __restrict__ Wv,  const float* __restrict__ bv,
    const float* __restrict__ Wq,
    const float* __restrict__ Wqt, const float* __restrict__ bqt,
    const float* __restrict__ Wkt, const float* __restrict__ bkt,
    const float* __restrict__ Wvt, const float* __restrict__ bvt,
    const float* __restrict__ Wg1a, const float* __restrict__ bg1a,
    const float* __restrict__ Wg1g, const float* __restrict__ bg1g,
    const float* __restrict__ Wg2a, const float* __restrict__ bg2a,
    const float* __restrict__ Wg2g, const float* __restrict__ bg2g,
    unsigned short* __restrict__ WcatB, float* __restrict__ biasg,
    unsigned short* __restrict__ WkvB,  float* __restrict__ bkv,
    unsigned short* __restrict__ WqB,
    unsigned short* __restrict__ WqktB, float* __restrict__ bqkt,
    unsigned short* __restrict__ Wg1B,  float* __restrict__ bg1,
    unsigned short* __restrict__ Wg2B,  float* __restrict__ bg2)
{
  int i = blockIdx.x*256 + threadIdx.x;
  if (i < GATE*KCAT) {
    int n = i / KCAT, k = i % KCAT;
    WcatB[i] = f2bf((k < TH_) ? Wih[n*TH_ + k] : Whh[n*ENC_ + (k - TH_)]);
  }
  if (i < GATE) biasg[i] = bih[i] + bhh[i];
  if (i < 2*ENC_*ENC_) {
    int n = i >> 7, k = i & 127;
    WkvB[i] = f2bf((n < ENC_) ? Wk[n*ENC_ + k] : Wv[(n-ENC_)*ENC_ + k]);
    Wg1B[i] = f2bf((n < ENC_) ? Wg1a[n*ENC_ + k] : Wg1g[(n-ENC_)*ENC_ + k]);
    Wg2B[i] = f2bf((n < ENC_) ? Wg2a[n*ENC_ + k] : Wg2g[(n-ENC_)*ENC_ + k]);
  }
  if (i < 2*ENC_) {
    bkv[i] = (i < ENC_) ? bk[i] : bv[i-ENC_];
    bg1[i] = (i < ENC_) ? bg1a[i] : bg1g[i-ENC_];
    bg2[i] = (i < ENC_) ? bg2a[i] : bg2g[i-ENC_];
  }
  if (i < ENC_*ENC_) WqB[i] = f2bf(Wq[i]);
  if (i < 3*ENC_*ENC_) {
    int n = i >> 7, k = i & 127;
    float w = (n < ENC_) ? Wqt[n*ENC_ + k] : (n < 2*ENC_) ? Wkt[(n-ENC_)*ENC_ + k]
                                                          : Wvt[(n-2*ENC_)*ENC_ + k];
    WqktB[i] = f2bf(w);
  }
  if (i < 3*ENC_) bqkt[i] = (i < ENC_) ? bqt[i] : (i < 2*ENC_) ? bkt[i-ENC_] : bvt[i-2*ENC_];
}

// ================= mask width detect / count / fill (proven) =========================
__device__ __forceinline__ int cellval(const unsigned char* m, long cell, int w) {
  long byte = cell * 128L * w;
  if (w == 1) return m[byte] != 0;
  if (w == 2) return *(const unsigned short*)(m + byte) != 0;
  if (w == 4) return *(const unsigned int*)(m + byte) != 0;
  return *(const unsigned long long*)(m + byte) != 0ULL;
}
__device__ __forceinline__ int cellconsist(const unsigned char* m, long cell, int w) {
  long byte = cell * 128L * w;
  if (w == 1) { unsigned char v = m[byte];
    for (int j = 1; j < 8; ++j) if (m[byte + j] != v) return 0; return 1; }
  if (w == 2) { unsigned short v = *(const unsigned short*)(m + byte);
    for (int j = 1; j < 8; ++j) if (*(const unsigned short*)(m + byte + 2L*j) != v) return 0; return 1; }
  if (w == 4) { unsigned int v = *(const unsigned int*)(m + byte);
    for (int j = 1; j < 8; ++j) if (*(const unsigned int*)(m + byte + 4L*j) != v) return 0; return 1; }
  unsigned long long v = *(const unsigned long long*)(m + byte);
  for (int j = 1; j < 8; ++j) if (*(const unsigned long long*)(m + byte + 8L*j) != v) return 0; return 1;
}

__global__ void k_detect(const unsigned char* __restrict__ mask, int* __restrict__ wsel)
{
  __shared__ int bad;
  int tid = threadIdx.x;
  int chosen = 0;
  for (int w = 1; w <= 8 && !chosen; w <<= 1) {
    if (tid == 0) bad = 0;
    __syncthreads();
    int ok = 1;
    for (int c = tid; c < 512; c += 256) ok &= cellconsist(mask, c, w);
    if (!ok) bad = 1;
    __syncthreads();
    if (!bad) chosen = w;
    __syncthreads();
  }
  if (tid == 0) *wsel = chosen ? chosen : 1;
}

__global__ void k_count(const unsigned char* __restrict__ mask,
                        const int* __restrict__ wsel, int* __restrict__ bcnt)
{
  __shared__ int sc[256];
  int tid = threadIdx.x;
  long cell = (long)blockIdx.x*256 + tid;
  sc[tid] = cellval(mask, cell, *wsel);
  __syncthreads();
  for (int off = 128; off; off >>= 1) {
    if (tid < off) sc[tid] += sc[tid + off];
    __syncthreads();
  }
  if (tid == 0) bcnt[blockIdx.x] = sc[0];
}

__global__ void k_fill(const unsigned char* __restrict__ mask,
                       const int* __restrict__ wsel, const int* __restrict__ bcnt,
                       int* __restrict__ nidx)
{
  __shared__ int sc[256];
  int tid = threadIdx.x, blk = blockIdx.x;
  long cell = (long)blk*256 + tid;
  int on = cellval(mask, cell, *wsel);
  sc[tid] = on;
  __syncthreads();
  for (int off = 1; off < 256; off <<= 1) {
    int v = (tid >= off) ? sc[tid - off] : 0;
    __syncthreads();
    sc[tid] += v;
    __syncthreads();
  }
  int base = 0;
  for (int i = 0; i < blk; ++i) base += bcnt[i];
  nidx[cell] = on ? (base + sc[tid] - 1) : -1;
}

// ================= kernel A: fused encode + LSTM chunk + kv/q projections ============
struct AP {
  const float *hist, *cls, *va, *nbrs, *nbrscls, *nbrsva;
  const float *W1, *b1;
  const unsigned short *Wcat, *Wkv, *Wq;
  const float *biasg, *bkv, *bq;
  float *hh;                 // (B,T,128) f32
  float *qbuf;               // (T,B,128) f32
  unsigned short *knvB;      // (tch,N,256) bf16
  unsigned short *Hsp;       // (MROWS,128) bf16 spill (swizzled content)
  float *csp;                // (NBLK2*512*8) f32 spill of c-registers
  int c0, tch;
};

// 272 blocks x 32 rows; 512 threads = 8 waves; wave w owns gate-channels w*16..+16
// (all 4 gates). H-part weights pinned in regs; encode hoisted to a chunk prologue.
__global__ __launch_bounds__(512, 2) void k_lstm(AP p)
{
  __shared__ unsigned short Hl[2*32*128];    // 16 KB, double-buffered, XOR-swizzled
  __shared__ unsigned short Xall[16*32*64];  // 64 KB, whole-chunk encodes, swizzled

  const int tid = threadIdx.x;
  const int w = tid >> 6, l = tid & 63;
  const int lr = l & 15, lk = (l >> 4) * 8, lq = (l >> 4) * 4;
  const int bi = blockIdx.x, bm = bi * 32;
  const bool ish = (bi < 16);

  // ---- H-part gate weights pinned: 4 gates x 4 ks ----
  bf16x8 wgh[4][4];
  #pragma unroll
  for (int g = 0; g < 4; ++g)
    #pragma unroll
    for (int ks = 0; ks < 4; ++ks)
      wgh[g][ks] = *(const bf16x8*)(p.Wcat + (long)(g*128 + w*16 + lr)*KCAT + 64 + ks*32 + lk);

  const int ch = w*16 + lr;
  const float bgi = p.biasg[ch], bgf = p.biasg[128+ch],
              bgg = p.biasg[256+ch], bgo = p.biasg[384+ch];

  // ---- chunk prologue: encode all (t,row) into Xall (col = lane l) ----
  {
    const float w1c0 = p.W1[l*5+0], w1c1 = p.W1[l*5+1], w1c2 = p.W1[l*5+2],
                w1c3 = p.W1[l*5+3], w1c4 = p.W1[l*5+4], b1c = p.b1[l];
    const float* ph = ish ? p.hist : p.nbrs;
    const float* pc = ish ? p.cls  : p.nbrscls;
    const float* pv = ish ? p.va   : p.nbrsva;
    for (int e = w; e < p.tch*32; e += 8) {
      int t4 = e >> 5, row = e & 31;
      long r = ish ? ((long)(p.c0 + t4)*B_ + bm + row)
                   : ((long)(p.c0 + t4)*N_ + (bm - B_) + row);
      float i0 = ph[r*2], i1 = ph[r*2+1], i2 = pc[r], i3 = pv[r*2], i4 = pv[r*2+1];
      float s = b1c + i0*w1c0 + i1*w1c1 + i2*w1c2 + i3*w1c3 + i4*w1c4;
      s = (s > 0.0f) ? s : expm1f(s);
      Xall[(t4*32 + row)*64 + (l ^ ((row & 7) << 3))] = f2bf(s);
    }
  }

  // ---- restore / init state ----
  float creg[2][4];
  if (p.c0 == 0) {
    for (int i = tid; i < 32*128; i += 512) Hl[i] = 0;
    #pragma unroll
    for (int mi = 0; mi < 2; ++mi)
      #pragma unroll
      for (int q = 0; q < 4; ++q) creg[mi][q] = 0.0f;
  } else {
    for (int i = tid; i < 32*128; i += 512) Hl[i] = p.Hsp[(long)bm*128 + i];
    #pragma unroll
    for (int mi = 0; mi < 2; ++mi)
      #pragma unroll
      for (int q = 0; q < 4; ++q) creg[mi][q] = p.csp[((long)bi*512 + tid)*8 + mi*4 + q];
  }
  __syncthreads();

  int cur = 0;
  for (int tl = 0; tl < p.tch; ++tl) {
    int t = p.c0 + tl;
    // ---- gate GEMM: 48 MFMA/wave ----
    f32x4 acc[4][2] = {};     // [gate][mi]
    #pragma unroll
    for (int ks = 0; ks < 2; ++ks) {          // K 0..63 from Xall (LDS)
      bf16x8 a[2];
      #pragma unroll
      for (int mi = 0; mi < 2; ++mi) {
        int row = mi*16 + lr;
        int col = (ks*32 + lk) ^ ((row & 7) << 3);
        a[mi] = *(const bf16x8*)(Xall + (tl*32 + row)*64 + col);
      }
      #pragma unroll
      for (int g = 0; g < 4; ++g) {
        bf16x8 b = *(const bf16x8*)(p.Wcat + (long)(g*128 + w*16 + lr)*KCAT + ks*32 + lk);
        #pragma unroll
        for (int mi = 0; mi < 2; ++mi)
          acc[g][mi] = __builtin_amdgcn_mfma_f32_16x16x32_bf16(a[mi], b, acc[g][mi], 0, 0, 0);
      }
    }
    #pragma unroll
    for (int ks = 0; ks < 4; ++ks) {          // K 64..191 from Hl[cur]
      bf16x8 a[2];
      #pragma unroll
      for (int mi = 0; mi < 2; ++mi) {
        int row = mi*16 + lr;
        int col = (ks*32 + lk) ^ ((row & 7) << 3);
        a[mi] = *(const bf16x8*)(Hl + cur*4096 + row*128 + col);
      }
      #pragma unroll
      for (int g = 0; g < 4; ++g)
        #pragma unroll
        for (int mi = 0; mi < 2; ++mi)
          acc[g][mi] = __builtin_amdgcn_mfma_f32_16x16x32_bf16(a[mi], wgh[g][ks], acc[g][mi], 0, 0, 0);
    }
    // ---- lane-local cell update (c in registers) ----
    int nxt = cur ^ 1;
    #pragma unroll
    for (int mi = 0; mi < 2; ++mi)
      #pragma unroll
      for (int q = 0; q < 4; ++q) {
        int row = mi*16 + lq + q;
        float gi = acc[0][mi][q] + bgi;
        float gf = acc[1][mi][q] + bgf;
        float gg = acc[2][mi][q] + bgg;
        float go = acc[3][mi][q] + bgo;
        float cc = sigm_f(gf)*creg[mi][q] + sigm_f(gi)*tanh_f(gg);
        creg[mi][q] = cc;
        float hv = sigm_f(go)*tanh_f(cc);
        Hl[nxt*4096 + row*128 + (ch ^ ((row & 7) << 3))] = f2bf(hv);
        if (ish) p.hh[((long)(bm + row)*T_ + t)*128 + ch] = hv;
      }
    __syncthreads();
    cur = nxt;
    // ---- projections from new H: kv (nbr blocks) / q (hist blocks) ----
    if (!ish) {
      f32x4 a2[2][2] = {};
      #pragma unroll
      for (int ks = 0; ks < 4; ++ks) {
        bf16x8 a[2];
        #pragma unroll
        for (int mi = 0; mi < 2; ++mi) {
          int row = mi*16 + lr;
          int col = (ks*32 + lk) ^ ((row & 7) << 3);
          a[mi] = *(const bf16x8*)(Hl + cur*4096 + row*128 + col);
        }
        #pragma unroll
        for (int ni = 0; ni < 2; ++ni) {
          bf16x8 b = *(const bf16x8*)(p.Wkv + (long)(w*32 + ni*16 + lr)*128 + ks*32 + lk);
          #pragma unroll
          for (int mi = 0; mi < 2; ++mi)
            a2[mi][ni] = __builtin_amdgcn_mfma_f32_16x16x32_bf16(a[mi], b, a2[mi][ni], 0, 0, 0);
        }
      }
      long nr = bm - B_;
      #pragma unroll
      for (int mi = 0; mi < 2; ++mi)
        #pragma unroll
        for (int ni = 0; ni < 2; ++ni) {
          int c2 = w*32 + ni*16 + lr;
          float bb = p.bkv[c2];
          #pragma unroll
          for (int q = 0; q < 4; ++q)
            p.knvB[((long)tl*N_ + nr + mi*16 + lq + q)*256 + c2] = f2bf(a2[mi][ni][q] + bb);
        }
    } else {
      f32x4 a2[2] = {};
      #pragma unroll
      for (int ks = 0; ks < 4; ++ks) {
        bf16x8 a[2];
        #pragma unroll
        for (int mi = 0; mi < 2; ++mi) {
          int row = mi*16 + lr;
          int col = (ks*32 + lk) ^ ((row & 7) << 3);
          a[mi] = *(const bf16x8*)(Hl + cur*4096 + row*128 + col);
        }
        bf16x8 b = *(const bf16x8*)(p.Wq + (long)(w*16 + lr)*128 + ks*32 + lk);
        #pragma unroll
        for (int mi = 0; mi < 2; ++mi)
          a2[mi] = __builtin_amdgcn_mfma_f32_16x16x32_bf16(a[mi], b, a2[mi], 0, 0, 0);
      }
      float bb = p.bq[ch];
      #pragma unroll
      for (int mi = 0; mi < 2; ++mi)
        #pragma unroll
        for (int q = 0; q < 4; ++q)
          p.qbuf[((long)t*B_ + bm + mi*16 + lq + q)*128 + ch] = a2[mi][q] + bb;
    }
    __syncthreads();
  }
  // ---- spill state for next chunk ----
  for (int i = tid; i < 32*128; i += 512) p.Hsp[(long)bm*128 + i] = Hl[cur*4096 + i];
  #pragma unroll
  for (int mi = 0; mi < 2; ++mi)
    #pragma unroll
    for (int q = 0; q < 4; ++q)
      p.csp[((long)bi*512 + tid)*8 + mi*4 + q] = creg[mi][q];
}

// ================= kernel B: spatial attention, one wave per (b, t) ==================
__global__ __launch_bounds__(256) void k_attn_sp(
    int c0, int ltch,
    const float* __restrict__ qbuf, const unsigned short* __restrict__ knvB,
    const float* __restrict__ bk, const float* __restrict__ bv,
    const int* __restrict__ nidx, unsigned short* __restrict__ spaB)
{
  int tid = threadIdx.x;
  int w = tid >> 6, l = tid & 63;
  __shared__ int sn[4][G_];
  __shared__ float aw[4][4][40];
  int gwid = blockIdx.x*4 + w;
  int b = gwid >> ltch;
  int tl = gwid & ((1 << ltch) - 1);
  int t = c0 + tl;
  if (l < G_) sn[w][l] = nidx[b*G_ + l];
  __syncthreads();
  float qA = qbuf[((long)t*B_ + b)*128 + l];
  float qB = qbuf[((long)t*B_ + b)*128 + 64 + l];
  for (int g = 0; g < G_; ++g) {
    int ni = sn[w][g];
    const unsigned short* kr = knvB + ((long)tl*N_ + ni)*256;
    float kA = (ni >= 0) ? bf2f(kr[l])      : bk[l];
    float kB = (ni >= 0) ? bf2f(kr[64 + l]) : bk[64 + l];
    float pA = qA*kA, pB = qB*kB;
    pA += __shfl_xor(pA, 16); pA += __shfl_xor(pA, 8); pA += __shfl_xor(pA, 4);
    pA += __shfl_xor(pA, 2);  pA += __shfl_xor(pA, 1);
    pB += __shfl_xor(pB, 16); pB += __shfl_xor(pB, 8); pB += __shfl_xor(pB, 4);
    pB += __shfl_xor(pB, 2);  pB += __shfl_xor(pB, 1);
    if ((l & 31) == 0) {
      int hb = l >> 5;
      aw[w][hb][g]     = pA * SCALE_;
      aw[w][2+hb][g]   = pB * SCALE_;
    }
  }
  __syncthreads();
  int hA = l >> 5, hB = 2 + (l >> 5);
  float mxA = -1e30f, mxB = -1e30f;
  for (int g = 0; g < G_; ++g) {
    mxA = fmaxf(mxA, aw[w][hA][g]);
    mxB = fmaxf(mxB, aw[w][hB][g]);
  }
  float sA = 0.f, sB = 0.f, oA = 0.f, oB = 0.f;
  for (int g = 0; g < G_; ++g) {
    int ni = sn[w][g];
    const unsigned short* vr = knvB + ((long)tl*N_ + ni)*256 + 128;
    float vA = (ni >= 0) ? bf2f(vr[l])      : bv[l];
    float vB = (ni >= 0) ? bf2f(vr[64 + l]) : bv[64 + l];
    float eA = expf(aw[w][hA][g] - mxA);
    float eB = expf(aw[w][hB][g] - mxB);
    sA += eA; sB += eB; oA += eA*vA; oB += eB*vB;
  }
  spaB[((long)b*T_ + t)*128 + l]      = f2bf(oA / sA);
  spaB[((long)b*T_ + t)*128 + 64 + l] = f2bf(oB / sB);
}

// ================= bf16 MFMA GEMM: C f32 out =========================================
__global__ __launch_bounds__(256) void k_gemm_bf16(
    const unsigned short* __restrict__ A, int lda,
    const unsigned short* __restrict__ W, int ldw,
    const float* __restrict__ bias,
    float* __restrict__ C, int ldc, int K)
{
  int tid = threadIdx.x;
  int w = tid >> 6, l = tid & 63;
  int lr = l & 15, lk = (l >> 4) * 8, lq = (l >> 4) * 4;
  int bm = blockIdx.x * 64;
  int bn = blockIdx.y * 128 + w * 32;
  f32x4 acc[4][2] = {};
  for (int k0 = 0; k0 < K; k0 += 32) {
    bf16x8 a[4], b[2];
    #pragma unroll
    for (int mi = 0; mi < 4; ++mi)
      a[mi] = *(const bf16x8*)(A + (long)(bm + mi*16 + lr)*lda + k0 + lk);
    #pragma unroll
    for (int ni = 0; ni < 2; ++ni)
      b[ni] = *(const bf16x8*)(W + (long)(bn + ni*16 + lr)*ldw + k0 + lk);
    #pragma unroll
    for (int mi = 0; mi < 4; ++mi)
      #pragma unroll
      for (int ni = 0; ni < 2; ++ni)
        acc[mi][ni] = __builtin_amdgcn_mfma_f32_16x16x32_bf16(a[mi], b[ni], acc[mi][ni], 0, 0, 0);
  }
  #pragma unroll
  for (int mi = 0; mi < 4; ++mi)
    #pragma unroll
    for (int ni = 0; ni < 2; ++ni) {
      int col = bn + ni*16 + lr;
      float bb = bias[col];
      #pragma unroll
      for (int q = 0; q < 4; ++q)
        C[(long)(bm + mi*16 + lq + q)*ldc + col] = acc[mi][ni][q] + bb;
    }
}

// same but bf16 output (for qkt)
__global__ __launch_bounds__(256) void k_gemm_bf16o(
    const unsigned short* __restrict__ A, int lda,
    const unsigned short* __restrict__ W, int ldw,
    const float* __restrict__ bias,
    unsigned short* __restrict__ C, int ldc, int K)
{
  int tid = threadIdx.x;
  int w = tid >> 6, l = tid & 63;
  int lr = l & 15, lk = (l >> 4) * 8, lq = (l >> 4) * 4;
  int bm = blockIdx.x * 64;
  int bn = blockIdx.y * 128 + w * 32;
  f32x4 acc[4][2] = {};
  for (int k0 = 0; k0 < K; k0 += 32) {
    bf16x8 a[4], b[2];
    #pragma unroll
    for (int mi = 0; mi < 4; ++mi)
      a[mi] = *(const bf16x8*)(A + (long)(bm + mi*16 + lr)*lda + k0 + lk);
    #pragma unroll
    for (int ni = 0; ni < 2; ++ni)
      b[ni] = *(const bf16x8*)(W + (long)(bn + ni*16 + lr)*ldw + k0 + lk);
    #pragma unroll
    for (int mi = 0; mi < 4; ++mi)
      #pragma unroll
      for (int ni = 0; ni < 2; ++ni)
        acc[mi][ni] = __builtin_amdgcn_mfma_f32_16x16x32_bf16(a[mi], b[ni], acc[mi][ni], 0, 0, 0);
  }
  #pragma unroll
  for (int mi = 0; mi < 4; ++mi)
    #pragma unroll
    for (int ni = 0; ni < 2; ++ni) {
      int col = bn + ni*16 + lr;
      float bb = bias[col];
      #pragma unroll
      for (int q = 0; q < 4; ++q)
        C[(long)(bm + mi*16 + lq + q)*ldc + col] = f2bf(acc[mi][ni][q] + bb);
    }
}

// ================= fused glu + residual add + layernorm ==============================
__global__ __launch_bounds__(256) void k_glu_addln(
    const float* __restrict__ t12, const float* __restrict__ res,
    const float* __restrict__ lg, const float* __restrict__ lb,
    float* __restrict__ sum_out, unsigned short* __restrict__ ln_bf16,
    float* __restrict__ ln_f32)
{
  int gtid = blockIdx.x*256 + threadIdx.x;
  int r = gtid >> 6;
  int l = threadIdx.x & 63;
  if (r >= B_*T_) return;
  long b4 = (long)r*256, b2 = (long)r*128;
  float xA = res[b2 + l]      + t12[b4 + l]      * sigm(t12[b4 + 128 + l]);
  float xB = res[b2 + 64 + l] + t12[b4 + 64 + l] * sigm(t12[b4 + 192 + l]);
  if (sum_out) { sum_out[b2 + l] = xA; sum_out[b2 + 64 + l] = xB; }
  float s = xA + xB, s2 = xA*xA + xB*xB;
  #pragma unroll
  for (int off = 32; off; off >>= 1) { s += __shfl_xor(s, off); s2 += __shfl_xor(s2, off); }
  float mean = s * (1.0f/128.0f);
  float var  = s2 * (1.0f/128.0f) - mean*mean;
  float inv  = rsqrtf(var + LNEPS);
  float oA = (xA - mean)*inv*lg[l]      + lb[l];
  float oB = (xB - mean)*inv*lg[64 + l] + lb[64 + l];
  if (ln_bf16) { ln_bf16[b2 + l] = f2bf(oA); ln_bf16[b2 + 64 + l] = f2bf(oB); }
  if (ln_f32)  { ln_f32[b2 + l] = oA;        ln_f32[b2 + 64 + l] = oB; }
}

// ================= temporal attention (bf16 qkt input) ===============================
__global__ __launch_bounds__(128) void k_attn_t(
    const unsigned short* __restrict__ qkt, unsigned short* __restrict__ out)
{
  int b = blockIdx.x, tid = threadIdx.x;
  __shared__ float sq[16][128], sk[16][128], sv[16][128];
  __shared__ float sc[16][4][16];
  for (int i = tid; i < T_*ENC_; i += 128) {
    int tt = i >> 7, j = i & 127;
    long a = ((long)b*T_ + tt)*384;
    sq[tt][j] = bf2f(qkt[a + j]);
    sk[tt][j] = bf2f(qkt[a + 128 + j]);
    sv[tt][j] = bf2f(qkt[a + 256 + j]);
  }
  __syncthreads();
  for (int e = tid; e < 1024; e += 128) {
    int t = e >> 6, s = (e >> 2) & 15, h2 = e & 3;
    float pp = 0.0f;
    #pragma unroll
    for (int d2 = 0; d2 < 32; ++d2) pp += sq[t][h2*32 + d2] * sk[s][h2*32 + d2];
    sc[t][h2][s] = pp * SCALE_;
  }
  __syncthreads();
  if (tid < 64) {
    int t = tid >> 2, h2 = tid & 3;
    float mx = -1e30f;
    for (int s = 0; s < 16; ++s) mx = fmaxf(mx, sc[t][h2][s]);
    float sum = 0.0f;
    for (int s = 0; s < 16; ++s) { float e2 = expf(sc[t][h2][s] - mx); sc[t][h2][s] = e2; sum += e2; }
    float inv = 1.0f / sum;
    for (int s = 0; s < 16; ++s) sc[t][h2][s] *= inv;
  }
  __syncthreads();
  int h2 = tid >> 5, d2 = tid & 31;
  for (int t = 0; t < 16; ++t) {
    float acc = 0.0f;
    for (int s = 0; s < 16; ++s) acc += sc[t][h2][s] * sv[s][h2*32 + d2];
    out[((long)b*T_ + t)*128 + tid] = f2bf(acc);
  }
}

extern "C" void kernel_launch(void* const* d_in, const int* in_sizes, int n_in,
                              void* d_out, int out_size, void* d_ws, size_t ws_size,
                              hipStream_t stream)
{
  const float* hist    = (const float*)d_in[0];
  const float* nbrs    = (const float*)d_in[1];
  const float* va      = (const float*)d_in[2];
  const float* nbrsva  = (const float*)d_in[3];
  const float* cls     = (const float*)d_in[6];
  const float* nbrscls = (const float*)d_in[7];
  const unsigned char* mask = (const unsigned char*)d_in[8];
  const float* W1  = (const float*)d_in[9];
  const float* b1  = (const float*)d_in[10];
  const float* Wih = (const float*)d_in[11];
  const float* Whh = (const float*)d_in[12];
  const float* bih = (const float*)d_in[13];
  const float* bhh = (const float*)d_in[14];
  const float* Wq  = (const float*)d_in[15];
  const float* bq  = (const float*)d_in[16];
  const float* Wk  = (const float*)d_in[17];
  const float* bk  = (const float*)d_in[18];
  const float* Wv  = (const float*)d_in[19];
  const float* bv  = (const float*)d_in[20];
  const float* Wg1a = (const float*)d_in[21];
  const float* bg1a = (const float*)d_in[22];
  const float* Wg1g = (const float*)d_in[23];
  const float* bg1g = (const float*)d_in[24];
  const float* Wqt = (const float*)d_in[25];
  const float* bqt = (const float*)d_in[26];
  const float* Wkt = (const float*)d_in[27];
  const float* bkt = (const float*)d_in[28];
  const float* Wvt = (const float*)d_in[29];
  const float* bvt = (const float*)d_in[30];
  const float* Wg2a = (const float*)d_in[31];
  const float* bg2a = (const float*)d_in[32];
  const float* Wg2g = (const float*)d_in[33];
  const float* bg2g = (const float*)d_in[34];
  const float* ln_g = (const float*)d_in[35];
  const float* ln_b = (const float*)d_in[36];

  // pick largest t-chunk the workspace affords
  size_t fixed = 0;
  {
    size_t items[] = {
      (size_t)GATE*KCAT*2, (size_t)GATE*4, (size_t)2*ENC_*ENC_*2, (size_t)2*ENC_*4,
      (size_t)ENC_*ENC_*2, (size_t)3*ENC_*ENC_*2, (size_t)3*ENC_*4,
      (size_t)2*ENC_*ENC_*2, (size_t)2*ENC_*4, (size_t)2*ENC_*ENC_*2, (size_t)2*ENC_*4,
      (size_t)B_*T_*ENC_*4,            // hh
      (size_t)T_*B_*ENC_*4,            // qbuf
      (size_t)MROWS*ENC_*2,            // Hsp
      (size_t)NBLK2*512*8*4,           // csp
      (size_t)B_*T_*ENC_*2,            // spaB
      (size_t)B_*T_*2*ENC_*4,          // t12
      (size_t)B_*T_*ENC_*4,            // S1
      (size_t)B_*T_*ENC_*2,            // valsB
      (size_t)B_*T_*3*ENC_*2,          // qktB
      (size_t)B_*T_*ENC_*2,            // atoB
      (size_t)B_*G_*4, (size_t)78*4, (size_t)4
    };
    for (size_t v : items) fixed += (v + 255) & ~(size_t)255;
  }
  int tch = 16, ltch = 4;
  while (tch > 2 && fixed + ((size_t)tch*N_*256*2 + 255) > ws_size) { tch >>= 1; ltch--; }

  char* base = (char*)d_ws;
  size_t off = 0;
  auto alloc = [&](size_t bytes) { char* r = base + off; off = (off + bytes + 255) & ~(size_t)255; return r; };
  unsigned short* WcatB = (unsigned short*)alloc(GATE*KCAT*2);
  float*          biasg = (float*)alloc(GATE*4);
  unsigned short* WkvB  = (unsigned short*)alloc(2*ENC_*ENC_*2);
  float*          bkv   = (float*)alloc(2*ENC_*4);
  unsigned short* WqB   = (unsigned short*)alloc(ENC_*ENC_*2);
  unsigned short* WqktB = (unsigned short*)alloc(3*ENC_*ENC_*2);
  float*          bqkt  = (float*)alloc(3*ENC_*4);
  unsigned short* Wg1B  = (unsigned short*)alloc(2*ENC_*ENC_*2);
  float*          bg1   = (float*)alloc(2*ENC_*4);
  unsigned short* Wg2B  = (unsigned short*)alloc(2*ENC_*ENC_*2);
  float*          bg2   = (float*)alloc(2*ENC_*4);
  float*          hh    = (float*)alloc((size_t)B_*T_*ENC_*4);
  float*          qbuf  = (float*)alloc((size_t)T_*B_*ENC_*4);
  unsigned short* Hsp   = (unsigned short*)alloc((size_t)MROWS*ENC_*2);
  float*          csp   = (float*)alloc((size_t)NBLK2*512*8*4);
  unsigned short* spaB  = (unsigned short*)alloc((size_t)B_*T_*ENC_*2);
  float*          t12   = (float*)alloc((size_t)B_*T_*2*ENC_*4);
  float*          S1    = (float*)alloc((size_t)B_*T_*ENC_*4);
  unsigned short* valsB = (unsigned short*)alloc((size_t)B_*T_*ENC_*2);
  unsigned short* qktB  = (unsigned short*)alloc((size_t)B_*T_*3*ENC_*2);
  unsigned short* atoB  = (unsigned short*)alloc((size_t)B_*T_*ENC_*2);
  int*            nidx  = (int*)alloc((size_t)B_*G_*4);
  int*            bcnt  = (int*)alloc(78*4);
  int*            wsel  = (int*)alloc(4);
  unsigned short* knvB  = (unsigned short*)alloc((size_t)tch*N_*256*2);

  k_prep<<<384, 256, 0, stream>>>(
      Wih, Whh, bih, bhh, Wk, bk, Wv, bv, Wq,
      Wqt, bqt, Wkt, bkt, Wvt, bvt,
      Wg1a, bg1a, Wg1g, bg1g, Wg2a, bg2a, Wg2g, bg2g,
      WcatB, biasg, WkvB, bkv, WqB, WqktB, bqkt, Wg1B, bg1, Wg2B, bg2);
  k_detect<<<1, 256, 0, stream>>>(mask, wsel);
  k_count<<<78, 256, 0, stream>>>(mask, wsel, bcnt);
  k_fill<<<78, 256, 0, stream>>>(mask, wsel, bcnt, nidx);

  AP ap;
  ap.hist = hist; ap.cls = cls; ap.va = va;
  ap.nbrs = nbrs; ap.nbrscls = nbrscls; ap.nbrsva = nbrsva;
  ap.W1 = W1; ap.b1 = b1;
  ap.Wcat = WcatB; ap.Wkv = WkvB; ap.Wq = WqB;
  ap.biasg = biasg; ap.bkv = bkv; ap.bq = bq;
  ap.hh = hh; ap.qbuf = qbuf; ap.knvB = knvB; ap.Hsp = Hsp; ap.csp = csp;
  ap.tch = tch;
  for (int c0 = 0; c0 < T_; c0 += tch) {
    ap.c0 = c0;
    k_lstm<<<NBLK2, 512, 0, stream>>>(ap);
    k_attn_sp<<<(B_*tch)/4, 256, 0, stream>>>(c0, ltch, qbuf, knvB, bk, bv, nidx, spaB);
  }

  // tail
  k_gemm_bf16<<<dim3((B_*T_)/64, 2), 256, 0, stream>>>(spaB, 128, Wg1B, 128, bg1, t12, 256, 128);
  k_glu_addln<<<(B_*T_*64)/256, 256, 0, stream>>>(t12, hh, ln_g, ln_b, S1, valsB, nullptr);
  k_gemm_bf16o<<<dim3((B_*T_)/64, 3), 256, 0, stream>>>(valsB, 128, WqktB, 128, bqkt, qktB, 384, 128);
  k_attn_t<<<B_, 128, 0, stream>>>(qktB, atoB);
  k_gemm_bf16<<<dim3((B_*T_)/64, 2), 256, 0, stream>>>(atoB, 128, Wg2B, 128, bg2, t12, 256, 128);
  k_glu_addln<<<(B_*T_*64)/256, 256, 0, stream>>>(t12, S1, ln_g, ln_b, nullptr, nullptr, (float*)d_out);
}

// Round 8
// 336.177 us; speedup vs baseline: 1.0152x; 1.0152x over previous
//
#include <hip/hip_runtime.h>
#include <math.h>

#define T_ 16
#define B_ 512
#define N_ 8192
#define G_ 39
#define ENC_ 128
#define TH_ 64
#define MROWS 8704          // B_ + N_
#define GATE 512            // 4*ENC_
#define KCAT 192            // TH_ + ENC_
#define SCALE_ 0.08838834764831845f
#define LNEPS 1e-5f
#define NBLK2 272           // MROWS/32

typedef short bf16x8 __attribute__((ext_vector_type(8)));
typedef float f32x4  __attribute__((ext_vector_type(4)));

__device__ __forceinline__ float sigm(float x){ return 1.0f/(1.0f+expf(-x)); }
__device__ __forceinline__ float rcpf(float x){ return __builtin_amdgcn_rcpf(x); }
__device__ __forceinline__ float sigm_f(float x){ return rcpf(1.0f + __expf(-x)); }
__device__ __forceinline__ float tanh_f(float x){ return 1.0f - 2.0f*rcpf(__expf(2.0f*x) + 1.0f); }
__device__ __forceinline__ unsigned short f2bf(float f){
  unsigned int u = __float_as_uint(f);
  unsigned int r = u + 0x7FFFu + ((u>>16)&1u);
  return (unsigned short)(r>>16);
}
__device__ __forceinline__ float bf2f(unsigned short h){
  return __uint_as_float(((unsigned int)h)<<16);
}

// ================= prep: convert weights to bf16, build fused biases =================
__global__ __launch_bounds__(256) void k_prep(
    const float* __restrict__ Wih, const float* __restrict__ Whh,
    const float* __restrict__ bih, const float* __restrict__ bhh,
    const float* __restrict__ Wk,  const float* __restrict__ bk,
    const float* __restrict__ Wv,  const float* __restrict__ bv,
    const float* __restrict__ Wq,
    const float* __restrict__ Wqt, const float* __restrict__ bqt,
    const float* __restrict__ Wkt, const float* __restrict__ bkt,
    const float* __restrict__ Wvt, const float* __restrict__ bvt,
    const float* __restrict__ Wg1a, const float* __restrict__ bg1a,
    const float* __restrict__ Wg1g, const float* __restrict__ bg1g,
    const float* __restrict__ Wg2a, const float* __restrict__ bg2a,
    const float* __restrict__ Wg2g, const float* __restrict__ bg2g,
    unsigned short* __restrict__ WcatB, float* __restrict__ biasg,
    unsigned short* __restrict__ WkvB,  float* __restrict__ bkv,
    unsigned short* __restrict__ WqB,
    unsigned short* __restrict__ WqktB, float* __restrict__ bqkt,
    unsigned short* __restrict__ Wg1B,  float* __restrict__ bg1,
    unsigned short* __restrict__ Wg2B,  float* __restrict__ bg2)
{
  int i = blockIdx.x*256 + threadIdx.x;
  if (i < GATE*KCAT) {
    int n = i / KCAT, k = i % KCAT;
    WcatB[i] = f2bf((k < TH_) ? Wih[n*TH_ + k] : Whh[n*ENC_ + (k - TH_)]);
  }
  if (i < GATE) biasg[i] = bih[i] + bhh[i];
  if (i < 2*ENC_*ENC_) {
    int n = i >> 7, k = i & 127;
    WkvB[i] = f2bf((n < ENC_) ? Wk[n*ENC_ + k] : Wv[(n-ENC_)*ENC_ + k]);
    Wg1B[i] = f2bf((n < ENC_) ? Wg1a[n*ENC_ + k] : Wg1g[(n-ENC_)*ENC_ + k]);
    Wg2B[i] = f2bf((n < ENC_) ? Wg2a[n*ENC_ + k] : Wg2g[(n-ENC_)*ENC_ + k]);
  }
  if (i < 2*ENC_) {
    bkv[i] = (i < ENC_) ? bk[i] : bv[i-ENC_];
    bg1[i] = (i < ENC_) ? bg1a[i] : bg1g[i-ENC_];
    bg2[i] = (i < ENC_) ? bg2a[i] : bg2g[i-ENC_];
  }
  if (i < ENC_*ENC_) WqB[i] = f2bf(Wq[i]);
  if (i < 3*ENC_*ENC_) {
    int n = i >> 7, k = i & 127;
    float w = (n < ENC_) ? Wqt[n*ENC_ + k] : (n < 2*ENC_) ? Wkt[(n-ENC_)*ENC_ + k]
                                                          : Wvt[(n-2*ENC_)*ENC_ + k];
    WqktB[i] = f2bf(w);
  }
  if (i < 3*ENC_) bqkt[i] = (i < ENC_) ? bqt[i] : (i < 2*ENC_) ? bkt[i-ENC_] : bvt[i-2*ENC_];
}

// ================= mask width detect / count / fill (proven) =========================
__device__ __forceinline__ int cellval(const unsigned char* m, long cell, int w) {
  long byte = cell * 128L * w;
  if (w == 1) return m[byte] != 0;
  if (w == 2) return *(const unsigned short*)(m + byte) != 0;
  if (w == 4) return *(const unsigned int*)(m + byte) != 0;
  return *(const unsigned long long*)(m + byte) != 0ULL;
}
__device__ __forceinline__ int cellconsist(const unsigned char* m, long cell, int w) {
  long byte = cell * 128L * w;
  if (w == 1) { unsigned char v = m[byte];
    for (int j = 1; j < 8; ++j) if (m[byte + j] != v) return 0; return 1; }
  if (w == 2) { unsigned short v = *(const unsigned short*)(m + byte);
    for (int j = 1; j < 8; ++j) if (*(const unsigned short*)(m + byte + 2L*j) != v) return 0; return 1; }
  if (w == 4) { unsigned int v = *(const unsigned int*)(m + byte);
    for (int j = 1; j < 8; ++j) if (*(const unsigned int*)(m + byte + 4L*j) != v) return 0; return 1; }
  unsigned long long v = *(const unsigned long long*)(m + byte);
  for (int j = 1; j < 8; ++j) if (*(const unsigned long long*)(m + byte + 8L*j) != v) return 0; return 1;
}

__global__ void k_detect(const unsigned char* __restrict__ mask, int* __restrict__ wsel)
{
  __shared__ int bad;
  int tid = threadIdx.x;
  int chosen = 0;
  for (int w = 1; w <= 8 && !chosen; w <<= 1) {
    if (tid == 0) bad = 0;
    __syncthreads();
    int ok = 1;
    for (int c = tid; c < 512; c += 256) ok &= cellconsist(mask, c, w);
    if (!ok) bad = 1;
    __syncthreads();
    if (!bad) chosen = w;
    __syncthreads();
  }
  if (tid == 0) *wsel = chosen ? chosen : 1;
}

__global__ void k_count(const unsigned char* __restrict__ mask,
                        const int* __restrict__ wsel, int* __restrict__ bcnt)
{
  __shared__ int sc[256];
  int tid = threadIdx.x;
  long cell = (long)blockIdx.x*256 + tid;
  sc[tid] = cellval(mask, cell, *wsel);
  __syncthreads();
  for (int off = 128; off; off >>= 1) {
    if (tid < off) sc[tid] += sc[tid + off];
    __syncthreads();
  }
  if (tid == 0) bcnt[blockIdx.x] = sc[0];
}

__global__ void k_fill(const unsigned char* __restrict__ mask,
                       const int* __restrict__ wsel, const int* __restrict__ bcnt,
                       int* __restrict__ nidx)
{
  __shared__ int sc[256];
  int tid = threadIdx.x, blk = blockIdx.x;
  long cell = (long)blk*256 + tid;
  int on = cellval(mask, cell, *wsel);
  sc[tid] = on;
  __syncthreads();
  for (int off = 1; off < 256; off <<= 1) {
    int v = (tid >= off) ? sc[tid - off] : 0;
    __syncthreads();
    sc[tid] += v;
    __syncthreads();
  }
  int base = 0;
  for (int i = 0; i < blk; ++i) base += bcnt[i];
  nidx[cell] = on ? (base + sc[tid] - 1) : -1;
}

// ================= kernel A: fused encode + LSTM chunk + kv/q projections ============
struct AP {
  const float *hist, *cls, *va, *nbrs, *nbrscls, *nbrsva;
  const float *W1, *b1;
  const unsigned short *Wcat, *Wkv, *Wq;
  const float *biasg, *bkv, *bq;
  float *hh;                 // (B,T,128) f32
  float *qbuf;               // (T,B,128) f32
  unsigned short *knvB;      // (tch,N,256) bf16
  unsigned short *Hsp;       // (MROWS,128) bf16 spill (swizzled content)
  float *csp;                // (NBLK2*512*8) f32 spill of c-registers
  int c0, tch;
};

// 272 blocks x 32 rows; 512 threads = 8 waves; wave w owns gate-channels w*16..+16
// (all 4 gates). H-part weights pinned in regs; encode staged in 8-t LDS phases.
// LDS = 16K (Hl) + 32K (Xall) = 48K  ->  2 blocks/CU resident (96K < 160K).
__global__ __launch_bounds__(512, 2) void k_lstm(AP p)
{
  __shared__ unsigned short Hl[2*32*128];    // 16 KB, double-buffered, XOR-swizzled
  __shared__ unsigned short Xall[8*32*64];   // 32 KB, 8-t encode phase, swizzled

  const int tid = threadIdx.x;
  const int w = tid >> 6, l = tid & 63;
  const int lr = l & 15, lk = (l >> 4) * 8, lq = (l >> 4) * 4;
  const int bi = blockIdx.x, bm = bi * 32;
  const bool ish = (bi < 16);

  // ---- H-part gate weights pinned: 4 gates x 4 ks ----
  bf16x8 wgh[4][4];
  #pragma unroll
  for (int g = 0; g < 4; ++g)
    #pragma unroll
    for (int ks = 0; ks < 4; ++ks)
      wgh[g][ks] = *(const bf16x8*)(p.Wcat + (long)(g*128 + w*16 + lr)*KCAT + 64 + ks*32 + lk);

  const int ch = w*16 + lr;
  const float bgi = p.biasg[ch], bgf = p.biasg[128+ch],
              bgg = p.biasg[256+ch], bgo = p.biasg[384+ch];

  // ---- encode-phase filler: t in [t0, t0+nt) -> Xall rows (col = lane l) ----
  const float w1c0 = p.W1[l*5+0], w1c1 = p.W1[l*5+1], w1c2 = p.W1[l*5+2],
              w1c3 = p.W1[l*5+3], w1c4 = p.W1[l*5+4], b1c = p.b1[l];
  const float* ph = ish ? p.hist : p.nbrs;
  const float* pc = ish ? p.cls  : p.nbrscls;
  const float* pv = ish ? p.va   : p.nbrsva;
  auto fill_x = [&](int t0, int nt) {
    for (int e = w; e < nt*32; e += 8) {
      int t4 = e >> 5, row = e & 31;
      long r = ish ? ((long)(p.c0 + t0 + t4)*B_ + bm + row)
                   : ((long)(p.c0 + t0 + t4)*N_ + (bm - B_) + row);
      float i0 = ph[r*2], i1 = ph[r*2+1], i2 = pc[r], i3 = pv[r*2], i4 = pv[r*2+1];
      float s = b1c + i0*w1c0 + i1*w1c1 + i2*w1c2 + i3*w1c3 + i4*w1c4;
      s = (s > 0.0f) ? s : expm1f(s);
      Xall[(t4*32 + row)*64 + (l ^ ((row & 7) << 3))] = f2bf(s);
    }
  };
  fill_x(0, (p.tch < 8) ? p.tch : 8);

  // ---- restore / init state ----
  float creg[2][4];
  if (p.c0 == 0) {
    for (int i = tid; i < 32*128; i += 512) Hl[i] = 0;
    #pragma unroll
    for (int mi = 0; mi < 2; ++mi)
      #pragma unroll
      for (int q = 0; q < 4; ++q) creg[mi][q] = 0.0f;
  } else {
    for (int i = tid; i < 32*128; i += 512) Hl[i] = p.Hsp[(long)bm*128 + i];
    #pragma unroll
    for (int mi = 0; mi < 2; ++mi)
      #pragma unroll
      for (int q = 0; q < 4; ++q) creg[mi][q] = p.csp[((long)bi*512 + tid)*8 + mi*4 + q];
  }
  __syncthreads();

  int cur = 0;
  for (int tl = 0; tl < p.tch; ++tl) {
    int t = p.c0 + tl;
    if (tl == 8) {                       // refill second encode phase
      fill_x(8, p.tch - 8);              // safe: all waves past gate(7) via barrier(7)
      __syncthreads();                   // refill visible before gate(8)
    }
    const int xi = tl & 7;
    // ---- gate GEMM: 48 MFMA/wave ----
    f32x4 acc[4][2] = {};     // [gate][mi]
    #pragma unroll
    for (int ks = 0; ks < 2; ++ks) {          // K 0..63 from Xall (LDS)
      bf16x8 a[2];
      #pragma unroll
      for (int mi = 0; mi < 2; ++mi) {
        int row = mi*16 + lr;
        int col = (ks*32 + lk) ^ ((row & 7) << 3);
        a[mi] = *(const bf16x8*)(Xall + (xi*32 + row)*64 + col);
      }
      #pragma unroll
      for (int g = 0; g < 4; ++g) {
        bf16x8 b = *(const bf16x8*)(p.Wcat + (long)(g*128 + w*16 + lr)*KCAT + ks*32 + lk);
        #pragma unroll
        for (int mi = 0; mi < 2; ++mi)
          acc[g][mi] = __builtin_amdgcn_mfma_f32_16x16x32_bf16(a[mi], b, acc[g][mi], 0, 0, 0);
      }
    }
    #pragma unroll
    for (int ks = 0; ks < 4; ++ks) {          // K 64..191 from Hl[cur]
      bf16x8 a[2];
      #pragma unroll
      for (int mi = 0; mi < 2; ++mi) {
        int row = mi*16 + lr;
        int col = (ks*32 + lk) ^ ((row & 7) << 3);
        a[mi] = *(const bf16x8*)(Hl + cur*4096 + row*128 + col);
      }
      #pragma unroll
      for (int g = 0; g < 4; ++g)
        #pragma unroll
        for (int mi = 0; mi < 2; ++mi)
          acc[g][mi] = __builtin_amdgcn_mfma_f32_16x16x32_bf16(a[mi], wgh[g][ks], acc[g][mi], 0, 0, 0);
    }
    // ---- lane-local cell update (c in registers) ----
    int nxt = cur ^ 1;
    #pragma unroll
    for (int mi = 0; mi < 2; ++mi)
      #pragma unroll
      for (int q = 0; q < 4; ++q) {
        int row = mi*16 + lq + q;
        float gi = acc[0][mi][q] + bgi;
        float gf = acc[1][mi][q] + bgf;
        float gg = acc[2][mi][q] + bgg;
        float go = acc[3][mi][q] + bgo;
        float cc = sigm_f(gf)*creg[mi][q] + sigm_f(gi)*tanh_f(gg);
        creg[mi][q] = cc;
        float hv = sigm_f(go)*tanh_f(cc);
        Hl[nxt*4096 + row*128 + (ch ^ ((row & 7) << 3))] = f2bf(hv);
        if (ish) p.hh[((long)(bm + row)*T_ + t)*128 + ch] = hv;
      }
    __syncthreads();                      // the only per-t barrier
    cur = nxt;
    // ---- projections from new H: kv (nbr blocks) / q (hist blocks) ----
    if (!ish) {
      f32x4 a2[2][2] = {};
      #pragma unroll
      for (int ks = 0; ks < 4; ++ks) {
        bf16x8 a[2];
        #pragma unroll
        for (int mi = 0; mi < 2; ++mi) {
          int row = mi*16 + lr;
          int col = (ks*32 + lk) ^ ((row & 7) << 3);
          a[mi] = *(const bf16x8*)(Hl + cur*4096 + row*128 + col);
        }
        #pragma unroll
        for (int ni = 0; ni < 2; ++ni) {
          bf16x8 b = *(const bf16x8*)(p.Wkv + (long)(w*32 + ni*16 + lr)*128 + ks*32 + lk);
          #pragma unroll
          for (int mi = 0; mi < 2; ++mi)
            a2[mi][ni] = __builtin_amdgcn_mfma_f32_16x16x32_bf16(a[mi], b, a2[mi][ni], 0, 0, 0);
        }
      }
      long nr = bm - B_;
      #pragma unroll
      for (int mi = 0; mi < 2; ++mi)
        #pragma unroll
        for (int ni = 0; ni < 2; ++ni) {
          int c2 = w*32 + ni*16 + lr;
          float bb = p.bkv[c2];
          #pragma unroll
          for (int q = 0; q < 4; ++q)
            p.knvB[((long)tl*N_ + nr + mi*16 + lq + q)*256 + c2] = f2bf(a2[mi][ni][q] + bb);
        }
    } else {
      f32x4 a2[2] = {};
      #pragma unroll
      for (int ks = 0; ks < 4; ++ks) {
        bf16x8 a[2];
        #pragma unroll
        for (int mi = 0; mi < 2; ++mi) {
          int row = mi*16 + lr;
          int col = (ks*32 + lk) ^ ((row & 7) << 3);
          a[mi] = *(const bf16x8*)(Hl + cur*4096 + row*128 + col);
        }
        bf16x8 b = *(const bf16x8*)(p.Wq + (long)(w*16 + lr)*128 + ks*32 + lk);
        #pragma unroll
        for (int mi = 0; mi < 2; ++mi)
          a2[mi] = __builtin_amdgcn_mfma_f32_16x16x32_bf16(a[mi], b, a2[mi], 0, 0, 0);
      }
      float bb = p.bq[ch];
      #pragma unroll
      for (int mi = 0; mi < 2; ++mi)
        #pragma unroll
        for (int q = 0; q < 4; ++q)
          p.qbuf[((long)t*B_ + bm + mi*16 + lq + q)*128 + ch] = a2[mi][q] + bb;
    }
    // no end-of-loop barrier: next gate reads Hl[cur] (read-read with proj);
    // next cell writes Hl[cur^1], whose last readers were pre-barrier(t).
  }
  // ---- spill state for next chunk ----
  for (int i = tid; i < 32*128; i += 512) p.Hsp[(long)bm*128 + i] = Hl[cur*4096 + i];
  #pragma unroll
  for (int mi = 0; mi < 2; ++mi)
    #pragma unroll
    for (int q = 0; q < 4; ++q)
      p.csp[((long)bi*512 + tid)*8 + mi*4 + q] = creg[mi][q];
}

// ================= kernel B: spatial attention, one wave per (b, t) ==================
__global__ __launch_bounds__(256) void k_attn_sp(
    int c0, int ltch,
    const float* __restrict__ qbuf, const unsigned short* __restrict__ knvB,
    const float* __restrict__ bk, const float* __restrict__ bv,
    const int* __restrict__ nidx, unsigned short* __restrict__ spaB)
{
  int tid = threadIdx.x;
  int w = tid >> 6, l = tid & 63;
  __shared__ int sn[4][G_];
  __shared__ float aw[4][4][40];
  int gwid = blockIdx.x*4 + w;
  int b = gwid >> ltch;
  int tl = gwid & ((1 << ltch) - 1);
  int t = c0 + tl;
  if (l < G_) sn[w][l] = nidx[b*G_ + l];
  __syncthreads();
  float qA = qbuf[((long)t*B_ + b)*128 + l];
  float qB = qbuf[((long)t*B_ + b)*128 + 64 + l];
  for (int g = 0; g < G_; ++g) {
    int ni = sn[w][g];
    const unsigned short* kr = knvB + ((long)tl*N_ + ni)*256;
    float kA = (ni >= 0) ? bf2f(kr[l])      : bk[l];
    float kB = (ni >= 0) ? bf2f(kr[64 + l]) : bk[64 + l];
    float pA = qA*kA, pB = qB*kB;
    pA += __shfl_xor(pA, 16); pA += __shfl_xor(pA, 8); pA += __shfl_xor(pA, 4);
    pA += __shfl_xor(pA, 2);  pA += __shfl_xor(pA, 1);
    pB += __shfl_xor(pB, 16); pB += __shfl_xor(pB, 8); pB += __shfl_xor(pB, 4);
    pB += __shfl_xor(pB, 2);  pB += __shfl_xor(pB, 1);
    if ((l & 31) == 0) {
      int hb = l >> 5;
      aw[w][hb][g]     = pA * SCALE_;
      aw[w][2+hb][g]   = pB * SCALE_;
    }
  }
  __syncthreads();
  int hA = l >> 5, hB = 2 + (l >> 5);
  float mxA = -1e30f, mxB = -1e30f;
  for (int g = 0; g < G_; ++g) {
    mxA = fmaxf(mxA, aw[w][hA][g]);
    mxB = fmaxf(mxB, aw[w][hB][g]);
  }
  float sA = 0.f, sB = 0.f, oA = 0.f, oB = 0.f;
  for (int g = 0; g < G_; ++g) {
    int ni = sn[w][g];
    const unsigned short* vr = knvB + ((long)tl*N_ + ni)*256 + 128;
    float vA = (ni >= 0) ? bf2f(vr[l])      : bv[l];
    float vB = (ni >= 0) ? bf2f(vr[64 + l]) : bv[64 + l];
    float eA = expf(aw[w][hA][g] - mxA);
    float eB = expf(aw[w][hB][g] - mxB);
    sA += eA; sB += eB; oA += eA*vA; oB += eB*vB;
  }
  spaB[((long)b*T_ + t)*128 + l]      = f2bf(oA / sA);
  spaB[((long)b*T_ + t)*128 + 64 + l] = f2bf(oB / sB);
}

// ================= bf16 MFMA GEMM: C f32 out =========================================
__global__ __launch_bounds__(256) void k_gemm_bf16(
    const unsigned short* __restrict__ A, int lda,
    const unsigned short* __restrict__ W, int ldw,
    const float* __restrict__ bias,
    float* __restrict__ C, int ldc, int K)
{
  int tid = threadIdx.x;
  int w = tid >> 6, l = tid & 63;
  int lr = l & 15, lk = (l >> 4) * 8, lq = (l >> 4) * 4;
  int bm = blockIdx.x * 64;
  int bn = blockIdx.y * 128 + w * 32;
  f32x4 acc[4][2] = {};
  for (int k0 = 0; k0 < K; k0 += 32) {
    bf16x8 a[4], b[2];
    #pragma unroll
    for (int mi = 0; mi < 4; ++mi)
      a[mi] = *(const bf16x8*)(A + (long)(bm + mi*16 + lr)*lda + k0 + lk);
    #pragma unroll
    for (int ni = 0; ni < 2; ++ni)
      b[ni] = *(const bf16x8*)(W + (long)(bn + ni*16 + lr)*ldw + k0 + lk);
    #pragma unroll
    for (int mi = 0; mi < 4; ++mi)
      #pragma unroll
      for (int ni = 0; ni < 2; ++ni)
        acc[mi][ni] = __builtin_amdgcn_mfma_f32_16x16x32_bf16(a[mi], b[ni], acc[mi][ni], 0, 0, 0);
  }
  #pragma unroll
  for (int mi = 0; mi < 4; ++mi)
    #pragma unroll
    for (int ni = 0; ni < 2; ++ni) {
      int col = bn + ni*16 + lr;
      float bb = bias[col];
      #pragma unroll
      for (int q = 0; q < 4; ++q)
        C[(long)(bm + mi*16 + lq + q)*ldc + col] = acc[mi][ni][q] + bb;
    }
}

// same but bf16 output (for qkt)
__global__ __launch_bounds__(256) void k_gemm_bf16o(
    const unsigned short* __restrict__ A, int lda,
    const unsigned short* __restrict__ W, int ldw,
    const float* __restrict__ bias,
    unsigned short* __restrict__ C, int ldc, int K)
{
  int tid = threadIdx.x;
  int w = tid >> 6, l = tid & 63;
  int lr = l & 15, lk = (l >> 4) * 8, lq = (l >> 4) * 4;
  int bm = blockIdx.x * 64;
  int bn = blockIdx.y * 128 + w * 32;
  f32x4 acc[4][2] = {};
  for (int k0 = 0; k0 < K; k0 += 32) {
    bf16x8 a[4], b[2];
    #pragma unroll
    for (int mi = 0; mi < 4; ++mi)
      a[mi] = *(const bf16x8*)(A + (long)(bm + mi*16 + lr)*lda + k0 + lk);
    #pragma unroll
    for (int ni = 0; ni < 2; ++ni)
      b[ni] = *(const bf16x8*)(W + (long)(bn + ni*16 + lr)*ldw + k0 + lk);
    #pragma unroll
    for (int mi = 0; mi < 4; ++mi)
      #pragma unroll
      for (int ni = 0; ni < 2; ++ni)
        acc[mi][ni] = __builtin_amdgcn_mfma_f32_16x16x32_bf16(a[mi], b[ni], acc[mi][ni], 0, 0, 0);
  }
  #pragma unroll
  for (int mi = 0; mi < 4; ++mi)
    #pragma unroll
    for (int ni = 0; ni < 2; ++ni) {
      int col = bn + ni*16 + lr;
      float bb = bias[col];
      #pragma unroll
      for (int q = 0; q < 4; ++q)
        C[(long)(bm + mi*16 + lq + q)*ldc + col] = f2bf(acc[mi][ni][q] + bb);
    }
}

// ================= fused glu + residual add + layernorm ==============================
__global__ __launch_bounds__(256) void k_glu_addln(
    const float* __restrict__ t12, const float* __restrict__ res,
    const float* __restrict__ lg, const float* __restrict__ lb,
    float* __restrict__ sum_out, unsigned short* __restrict__ ln_bf16,
    float* __restrict__ ln_f32)
{
  int gtid = blockIdx.x*256 + threadIdx.x;
  int r = gtid >> 6;
  int l = threadIdx.x & 63;
  if (r >= B_*T_) return;
  long b4 = (long)r*256, b2 = (long)r*128;
  float xA = res[b2 + l]      + t12[b4 + l]      * sigm(t12[b4 + 128 + l]);
  float xB = res[b2 + 64 + l] + t12[b4 + 64 + l] * sigm(t12[b4 + 192 + l]);
  if (sum_out) { sum_out[b2 + l] = xA; sum_out[b2 + 64 + l] = xB; }
  float s = xA + xB, s2 = xA*xA + xB*xB;
  #pragma unroll
  for (int off = 32; off; off >>= 1) { s += __shfl_xor(s, off); s2 += __shfl_xor(s2, off); }
  float mean = s * (1.0f/128.0f);
  float var  = s2 * (1.0f/128.0f) - mean*mean;
  float inv  = rsqrtf(var + LNEPS);
  float oA = (xA - mean)*inv*lg[l]      + lb[l];
  float oB = (xB - mean)*inv*lg[64 + l] + lb[64 + l];
  if (ln_bf16) { ln_bf16[b2 + l] = f2bf(oA); ln_bf16[b2 + 64 + l] = f2bf(oB); }
  if (ln_f32)  { ln_f32[b2 + l] = oA;        ln_f32[b2 + 64 + l] = oB; }
}

// ================= temporal attention (bf16 qkt input) ===============================
__global__ __launch_bounds__(128) void k_attn_t(
    const unsigned short* __restrict__ qkt, unsigned short* __restrict__ out)
{
  int b = blockIdx.x, tid = threadIdx.x;
  __shared__ float sq[16][128], sk[16][128], sv[16][128];
  __shared__ float sc[16][4][16];
  for (int i = tid; i < T_*ENC_; i += 128) {
    int tt = i >> 7, j = i & 127;
    long a = ((long)b*T_ + tt)*384;
    sq[tt][j] = bf2f(qkt[a + j]);
    sk[tt][j] = bf2f(qkt[a + 128 + j]);
    sv[tt][j] = bf2f(qkt[a + 256 + j]);
  }
  __syncthreads();
  for (int e = tid; e < 1024; e += 128) {
    int t = e >> 6, s = (e >> 2) & 15, h2 = e & 3;
    float pp = 0.0f;
    #pragma unroll
    for (int d2 = 0; d2 < 32; ++d2) pp += sq[t][h2*32 + d2] * sk[s][h2*32 + d2];
    sc[t][h2][s] = pp * SCALE_;
  }
  __syncthreads();
  if (tid < 64) {
    int t = tid >> 2, h2 = tid & 3;
    float mx = -1e30f;
    for (int s = 0; s < 16; ++s) mx = fmaxf(mx, sc[t][h2][s]);
    float sum = 0.0f;
    for (int s = 0; s < 16; ++s) { float e2 = expf(sc[t][h2][s] - mx); sc[t][h2][s] = e2; sum += e2; }
    float inv = 1.0f / sum;
    for (int s = 0; s < 16; ++s) sc[t][h2][s] *= inv;
  }
  __syncthreads();
  int h2 = tid >> 5, d2 = tid & 31;
  for (int t = 0; t < 16; ++t) {
    float acc = 0.0f;
    for (int s = 0; s < 16; ++s) acc += sc[t][h2][s] * sv[s][h2*32 + d2];
    out[((long)b*T_ + t)*128 + tid] = f2bf(acc);
  }
}

extern "C" void kernel_launch(void* const* d_in, const int* in_sizes, int n_in,
                              void* d_out, int out_size, void* d_ws, size_t ws_size,
                              hipStream_t stream)
{
  const float* hist    = (const float*)d_in[0];
  const float* nbrs    = (const float*)d_in[1];
  const float* va      = (const float*)d_in[2];
  const float* nbrsva  = (const float*)d_in[3];
  const float* cls     = (const float*)d_in[6];
  const float* nbrscls = (const float*)d_in[7];
  const unsigned char* mask = (const unsigned char*)d_in[8];
  const float* W1  = (const float*)d_in[9];
  const float* b1  = (const float*)d_in[10];
  const float* Wih = (const float*)d_in[11];
  const float* Whh = (const float*)d_in[12];
  const float* bih = (const float*)d_in[13];
  const float* bhh = (const float*)d_in[14];
  const float* Wq  = (const float*)d_in[15];
  const float* bq  = (const float*)d_in[16];
  const float* Wk  = (const float*)d_in[17];
  const float* bk  = (const float*)d_in[18];
  const float* Wv  = (const float*)d_in[19];
  const float* bv  = (const float*)d_in[20];
  const float* Wg1a = (const float*)d_in[21];
  const float* bg1a = (const float*)d_in[22];
  const float* Wg1g = (const float*)d_in[23];
  const float* bg1g = (const float*)d_in[24];
  const float* Wqt = (const float*)d_in[25];
  const float* bqt = (const float*)d_in[26];
  const float* Wkt = (const float*)d_in[27];
  const float* bkt = (const float*)d_in[28];
  const float* Wvt = (const float*)d_in[29];
  const float* bvt = (const float*)d_in[30];
  const float* Wg2a = (const float*)d_in[31];
  const float* bg2a = (const float*)d_in[32];
  const float* Wg2g = (const float*)d_in[33];
  const float* bg2g = (const float*)d_in[34];
  const float* ln_g = (const float*)d_in[35];
  const float* ln_b = (const float*)d_in[36];

  // pick largest t-chunk the workspace affords
  size_t fixed = 0;
  {
    size_t items[] = {
      (size_t)GATE*KCAT*2, (size_t)GATE*4, (size_t)2*ENC_*ENC_*2, (size_t)2*ENC_*4,
      (size_t)ENC_*ENC_*2, (size_t)3*ENC_*ENC_*2, (size_t)3*ENC_*4,
      (size_t)2*ENC_*ENC_*2, (size_t)2*ENC_*4, (size_t)2*ENC_*ENC_*2, (size_t)2*ENC_*4,
      (size_t)B_*T_*ENC_*4,            // hh
      (size_t)T_*B_*ENC_*4,            // qbuf
      (size_t)MROWS*ENC_*2,            // Hsp
      (size_t)NBLK2*512*8*4,           // csp
      (size_t)B_*T_*ENC_*2,            // spaB
      (size_t)B_*T_*2*ENC_*4,          // t12
      (size_t)B_*T_*ENC_*4,            // S1
      (size_t)B_*T_*ENC_*2,            // valsB
      (size_t)B_*T_*3*ENC_*2,          // qktB
      (size_t)B_*T_*ENC_*2,            // atoB
      (size_t)B_*G_*4, (size_t)78*4, (size_t)4
    };
    for (size_t v : items) fixed += (v + 255) & ~(size_t)255;
  }
  int tch = 16, ltch = 4;
  while (tch > 2 && fixed + ((size_t)tch*N_*256*2 + 255) > ws_size) { tch >>= 1; ltch--; }

  char* base = (char*)d_ws;
  size_t off = 0;
  auto alloc = [&](size_t bytes) { char* r = base + off; off = (off + bytes + 255) & ~(size_t)255; return r; };
  unsigned short* WcatB = (unsigned short*)alloc(GATE*KCAT*2);
  float*          biasg = (float*)alloc(GATE*4);
  unsigned short* WkvB  = (unsigned short*)alloc(2*ENC_*ENC_*2);
  float*          bkv   = (float*)alloc(2*ENC_*4);
  unsigned short* WqB   = (unsigned short*)alloc(ENC_*ENC_*2);
  unsigned short* WqktB = (unsigned short*)alloc(3*ENC_*ENC_*2);
  float*          bqkt  = (float*)alloc(3*ENC_*4);
  unsigned short* Wg1B  = (unsigned short*)alloc(2*ENC_*ENC_*2);
  float*          bg1   = (float*)alloc(2*ENC_*4);
  unsigned short* Wg2B  = (unsigned short*)alloc(2*ENC_*ENC_*2);
  float*          bg2   = (float*)alloc(2*ENC_*4);
  float*          hh    = (float*)alloc((size_t)B_*T_*ENC_*4);
  float*          qbuf  = (float*)alloc((size_t)T_*B_*ENC_*4);
  unsigned short* Hsp   = (unsigned short*)alloc((size_t)MROWS*ENC_*2);
  float*          csp   = (float*)alloc((size_t)NBLK2*512*8*4);
  unsigned short* spaB  = (unsigned short*)alloc((size_t)B_*T_*ENC_*2);
  float*          t12   = (float*)alloc((size_t)B_*T_*2*ENC_*4);
  float*          S1    = (float*)alloc((size_t)B_*T_*ENC_*4);
  unsigned short* valsB = (unsigned short*)alloc((size_t)B_*T_*ENC_*2);
  unsigned short* qktB  = (unsigned short*)alloc((size_t)B_*T_*3*ENC_*2);
  unsigned short* atoB  = (unsigned short*)alloc((size_t)B_*T_*ENC_*2);
  int*            nidx  = (int*)alloc((size_t)B_*G_*4);
  int*            bcnt  = (int*)alloc(78*4);
  int*            wsel  = (int*)alloc(4);
  unsigned short* knvB  = (unsigned short*)alloc((size_t)tch*N_*256*2);

  k_prep<<<384, 256, 0, stream>>>(
      Wih, Whh, bih, bhh, Wk, bk, Wv, bv, Wq,
      Wqt, bqt, Wkt, bkt, Wvt, bvt,
      Wg1a, bg1a, Wg1g, bg1g, Wg2a, bg2a, Wg2g, bg2g,
      WcatB, biasg, WkvB, bkv, WqB, WqktB, bqkt, Wg1B, bg1, Wg2B, bg2);
  k_detect<<<1, 256, 0, stream>>>(mask, wsel);
  k_count<<<78, 256, 0, stream>>>(mask, wsel, bcnt);
  k_fill<<<78, 256, 0, stream>>>(mask, wsel, bcnt, nidx);

  AP ap;
  ap.hist = hist; ap.cls = cls; ap.va = va;
  ap.nbrs = nbrs; ap.nbrscls = nbrscls; ap.nbrsva = nbrsva;
  ap.W1 = W1; ap.b1 = b1;
  ap.Wcat = WcatB; ap.Wkv = WkvB; ap.Wq = WqB;
  ap.biasg = biasg; ap.bkv = bkv; ap.bq = bq;
  ap.hh = hh; ap.qbuf = qbuf; ap.knvB = knvB; ap.Hsp = Hsp; ap.csp = csp;
  ap.tch = tch;
  for (int c0 = 0; c0 < T_; c0 += tch) {
    ap.c0 = c0;
    k_lstm<<<NBLK2, 512, 0, stream>>>(ap);
    k_attn_sp<<<(B_*tch)/4, 256, 0, stream>>>(c0, ltch, qbuf, knvB, bk, bv, nidx, spaB);
  }

  // tail
  k_gemm_bf16<<<dim3((B_*T_)/64, 2), 256, 0, stream>>>(spaB, 128, Wg1B, 128, bg1, t12, 256, 128);
  k_glu_addln<<<(B_*T_*64)/256, 256, 0, stream>>>(t12, hh, ln_g, ln_b, S1, valsB, nullptr);
  k_gemm_bf16o<<<dim3((B_*T_)/64, 3), 256, 0, stream>>>(valsB, 128, WqktB, 128, bqkt, qktB, 384, 128);
  k_attn_t<<<B_, 128, 0, stream>>>(qktB, atoB);
  k_gemm_bf16<<<dim3((B_*T_)/64, 2), 256, 0, stream>>>(atoB, 128, Wg2B, 128, bg2, t12, 256, 128);
  k_glu_addln<<<(B_*T_*64)/256, 256, 0, stream>>>(t12, S1, ln_g, ln_b, nullptr, nullptr, (float*)d_out);
}